// Round 5
// baseline (48.591 us; speedup 1.0000x reference)
//
#include <hip/hip_runtime.h>
#include <stdint.h>

// BERT input representation, round 5: algebraic restructure.
//   out[r][c] = x'[r] @ W[:,c]  +  pe2[r&511][c]
// where x' = x + broadcast(seg-reduce of x)   (seg commutes through GEMM)
//       pe2 = PE + b_emb*(1+Sum w) + b_seg    (2 MB, L2-resident)
// Main kernel: pure bf16 MFMA GEMM + f32x4 bias load + store. No LDS, no
// barriers, no shfl, no trig in the hot kernel.
//
// d_ws layout: [0,128KB) W bf16 A-frag | [128KB,+2MB) pe2 f32 | [+2MB,+4MB) x' bf16

typedef __attribute__((ext_vector_type(8))) short short8;
typedef __attribute__((ext_vector_type(4))) float f32x4;
typedef __attribute__((ext_vector_type(4))) unsigned short u16x4;

#define D_DIM 1024
#define WS_PE_OFF 131072
#define WS_X_OFF (131072 + 2097152)

__device__ __forceinline__ unsigned short f2bf(float f) {
  unsigned u = __float_as_uint(f);
  u = (u + 0x7FFFu + ((u >> 16) & 1u)) >> 16;  // RNE f32 -> bf16
  return (unsigned short)u;
}

__global__ __launch_bounds__(256) void bert_setup(
    const float* __restrict__ x, const float* __restrict__ W,
    const float* __restrict__ b_emb, const float* __restrict__ w_seg,
    const float* __restrict__ b_seg, unsigned short* __restrict__ wsW,
    float* __restrict__ wsPE, unsigned short* __restrict__ wsX) {
  const int bid = blockIdx.x;
  const int tid = threadIdx.x;
  if (bid < 1024) {
    // ---- x' = x + seg broadcast; one wave per 8-row segment group ----
    const int lane = tid & 63;
    const int gg = bid * 4 + (tid >> 6);  // group 0..4095
    const size_t base = (size_t)gg * 512; // 8 rows x 64 f32, contiguous
    const int sl = lane >> 4;             // this lane's rows: sl and sl+4
    const int c0 = (lane & 15) * 4;       // this lane's 4 cols
    const float4 v1 = *reinterpret_cast<const float4*>(x + base + lane * 4);
    const float4 v2 = *reinterpret_cast<const float4*>(x + base + 256 + lane * 4);
    const float wa = w_seg[sl], wb = w_seg[sl + 4];
    float q0 = wa * v1.x + wb * v2.x;
    float q1 = wa * v1.y + wb * v2.y;
    float q2 = wa * v1.z + wb * v2.z;
    float q3 = wa * v1.w + wb * v2.w;
    q0 += __shfl_xor(q0, 16); q1 += __shfl_xor(q1, 16);
    q2 += __shfl_xor(q2, 16); q3 += __shfl_xor(q3, 16);
    q0 += __shfl_xor(q0, 32); q1 += __shfl_xor(q1, 32);
    q2 += __shfl_xor(q2, 32); q3 += __shfl_xor(q3, 32);
    // q* = sum_s w[s]*x[row s][c] for this lane's cols
    u16x4 o1, o2;
    o1[0] = f2bf(v1.x + q0); o1[1] = f2bf(v1.y + q1);
    o1[2] = f2bf(v1.z + q2); o1[3] = f2bf(v1.w + q3);
    o2[0] = f2bf(v2.x + q0); o2[1] = f2bf(v2.y + q1);
    o2[2] = f2bf(v2.z + q2); o2[3] = f2bf(v2.w + q3);
    *reinterpret_cast<u16x4*>(wsX + base + sl * 64 + c0) = o1;
    *reinterpret_cast<u16x4*>(wsX + base + (sl + 4) * 64 + c0) = o2;
  } else if (bid < 1536) {
    // ---- pe2[s][c] = PE + b_emb[c]*(1+Sw) + b_seg  (131072 f32x4) ----
    const int t = (bid - 1024) * 256 + tid;
    const int s = t >> 8;
    const int c0 = (t & 255) * 4;
    float Sw = 0.f;
#pragma unroll
    for (int i = 0; i < 8; ++i) Sw += w_seg[i];
    const float inv2pi = 0.15915494309189535f;
    const float KLOG = 0.02595256324130752f;  // log2(10000)/512
    const float d0 = exp2f(-(float)(c0 >> 1) * KLOG) * inv2pi;
    const float d1 = exp2f(-(float)((c0 >> 1) + 1) * KLOG) * inv2pi;
    const float fs = (float)s;
    const float4 eb = *reinterpret_cast<const float4*>(b_emb + c0);
    const float cb = b_seg[0];
    float4 pv;
    pv.x = __builtin_amdgcn_sinf(__builtin_amdgcn_fractf(fs * d0)) + eb.x * (1.f + Sw) + cb;
    pv.y = __builtin_amdgcn_sinf(__builtin_amdgcn_fractf(fs * d0 + 0.25f)) + eb.y * (1.f + Sw) + cb;
    pv.z = __builtin_amdgcn_sinf(__builtin_amdgcn_fractf(fs * d1)) + eb.z * (1.f + Sw) + cb;
    pv.w = __builtin_amdgcn_sinf(__builtin_amdgcn_fractf(fs * d1 + 0.25f)) + eb.w * (1.f + Sw) + cb;
    *reinterpret_cast<float4*>(wsPE + (size_t)t * 4) = pv;
  } else {
    // ---- W -> bf16 A-fragment layout (verified in rounds 2/4) ----
    // t=(cfg*2+kf)*64+lane; elem i = W[kf*32+(lane>>4)*8+i][cfg*16+(lane&15)]
    const int t = (bid - 1536) * 256 + tid;  // 0..8191
    const int cfg = t >> 7;
    const int kf = (t >> 6) & 1;
    const int lane = t & 63;
    const int col = cfg * 16 + (lane & 15);
    const int k0 = kf * 32 + ((lane >> 4) << 3);
    short8 o;
#pragma unroll
    for (int i = 0; i < 8; ++i)
      o[i] = (short)f2bf(W[(size_t)(k0 + i) * D_DIM + col]);
    *reinterpret_cast<short8*>(wsW + (size_t)t * 8) = o;
  }
}

__global__ __launch_bounds__(256) void bert_main(
    const unsigned short* __restrict__ wsX,
    const unsigned short* __restrict__ wsW, const float* __restrict__ wsPE,
    float* __restrict__ out) {
  const int tid = threadIdx.x;
  const int lane = tid & 63;
  const int wave = tid >> 6;
  const int bid = blockIdx.x;
  // XCD swizzle: XCD k owns mblks == k (mod 8) -> x' rows read once per XCD,
  // and each XCD touches only a 256 KB slice of pe2 (rows k*64..k*64+63).
  const int nblk = (bid >> 3) & 7;
  const int mblk = (bid & 7) | ((bid >> 6) << 3);
  const int mbase = mblk * 64;
  const int nbase = nblk * 128;
  const int mw = wave >> 1;
  const int nw = wave & 1;
  const int L15 = lane & 15;
  const int g = lane >> 4;

  // ---- A fragments: W (L2-hot) ----
  short8 aW[4][2];
#pragma unroll
  for (int cf = 0; cf < 4; ++cf)
#pragma unroll
    for (int kf = 0; kf < 2; ++kf) {
      const int cfg = (nbase >> 4) + nw * 4 + cf;
      aW[cf][kf] = *reinterpret_cast<const short8*>(
          wsW + ((size_t)(cfg * 2 + kf) * 64 + lane) * 8);
    }

  // ---- B fragments: x' rows ----
  short8 bX[2][2];
#pragma unroll
  for (int rf = 0; rf < 2; ++rf)
#pragma unroll
    for (int kf = 0; kf < 2; ++kf) {
      const int row = mbase + mw * 32 + rf * 16 + L15;
      bX[rf][kf] = *reinterpret_cast<const short8*>(
          wsX + (size_t)row * 64 + kf * 32 + g * 8);
    }

  // ---- MFMA ----
  f32x4 acc[4][2];
#pragma unroll
  for (int cf = 0; cf < 4; ++cf)
#pragma unroll
    for (int rf = 0; rf < 2; ++rf) {
      f32x4 c = {0.f, 0.f, 0.f, 0.f};
      c = __builtin_amdgcn_mfma_f32_16x16x32_bf16(aW[cf][0], bX[rf][0], c, 0, 0, 0);
      c = __builtin_amdgcn_mfma_f32_16x16x32_bf16(aW[cf][1], bX[rf][1], c, 0, 0, 0);
      acc[cf][rf] = c;
    }

  // ---- epilogue: one L2-hit f32x4 bias load + 4 adds per fragment ----
#pragma unroll
  for (int cf = 0; cf < 4; ++cf) {
    const int colq = nbase + nw * 64 + cf * 16 + g * 4;
#pragma unroll
    for (int rf = 0; rf < 2; ++rf) {
      const int row = mbase + mw * 32 + rf * 16 + L15;
      const f32x4 a = acc[cf][rf];
      const float4 pe = *reinterpret_cast<const float4*>(
          wsPE + (size_t)(row & 511) * D_DIM + colq);
      float4 o;
      o.x = a[0] + pe.x;
      o.y = a[1] + pe.y;
      o.z = a[2] + pe.z;
      o.w = a[3] + pe.w;
      *reinterpret_cast<float4*>(out + (size_t)row * D_DIM + colq) = o;
    }
  }
}

extern "C" void kernel_launch(void* const* d_in, const int* in_sizes, int n_in,
                              void* d_out, int out_size, void* d_ws,
                              size_t ws_size, hipStream_t stream) {
  const float* x = (const float*)d_in[0];
  const float* W = (const float*)d_in[1];
  const float* b_emb = (const float*)d_in[2];
  const float* w_seg = (const float*)d_in[3];
  const float* b_seg = (const float*)d_in[4];
  float* out = (float*)d_out;

  unsigned short* wsW = (unsigned short*)d_ws;                      // 128 KB
  float* wsPE = (float*)((char*)d_ws + WS_PE_OFF);                  // 2 MB
  unsigned short* wsX = (unsigned short*)((char*)d_ws + WS_X_OFF);  // 4 MB

  bert_setup<<<1568, 256, 0, stream>>>(x, W, b_emb, w_seg, b_seg, wsW, wsPE, wsX);
  bert_main<<<4096, 256, 0, stream>>>(wsX, wsW, wsPE, out);
}

// Round 6
// 40.275 us; speedup vs baseline: 1.2065x; 1.2065x over previous
//
#include <hip/hip_runtime.h>
#include <stdint.h>

// BERT input representation, round 6: fix the store pattern.
//   out[r][c] = x'[r] @ W[:,c] + pe2[r&511][c]
//   x'  = x + broadcast(seg-reduce x)   (seg commutes through the GEMM)
//   pe2 = PE + b_emb*(1+Sum w) + b_seg  (2 MB, L2-resident)
// Evidence R1-R5: 16-row x 64B-segment stores cap at ~3.7 TB/s; fillBuffer's
// 1KB-contiguous waves hit 6.5. Main kernel now routes acc through a 32KB
// swizzled LDS buffer so each wave store (and its pe2 read) is 1KB contiguous.
// Flat structure: 1 tile/block (32 rows x 256 cols), 1 barrier, no loop.
//
// d_ws: [0,128KB) W bf16 A-frag | [128KB,+2MB) pe2 f32 | [+2MB,+4MB) x' bf16

typedef __attribute__((ext_vector_type(8))) short short8;
typedef __attribute__((ext_vector_type(4))) float f32x4;
typedef __attribute__((ext_vector_type(4))) unsigned short u16x4;

#define D_DIM 1024
#define WS_PE_OFF 131072
#define WS_X_OFF (131072 + 2097152)

__device__ __forceinline__ unsigned short f2bf(float f) {
  unsigned u = __float_as_uint(f);
  u = (u + 0x7FFFu + ((u >> 16) & 1u)) >> 16;  // RNE f32 -> bf16
  return (unsigned short)u;
}

__global__ __launch_bounds__(256) void bert_setup(
    const float* __restrict__ x, const float* __restrict__ W,
    const float* __restrict__ b_emb, const float* __restrict__ w_seg,
    const float* __restrict__ b_seg, unsigned short* __restrict__ wsW,
    float* __restrict__ wsPE, unsigned short* __restrict__ wsX) {
  const int bid = blockIdx.x;
  const int tid = threadIdx.x;
  if (bid < 1024) {
    // ---- x' = x + seg broadcast; one wave per 8-row segment group ----
    const int lane = tid & 63;
    const int gg = bid * 4 + (tid >> 6);  // group 0..4095
    const size_t base = (size_t)gg * 512; // 8 rows x 64 f32, contiguous
    const int sl = lane >> 4;             // this lane's rows: sl and sl+4
    const int c0 = (lane & 15) * 4;       // this lane's 4 cols
    const float4 v1 = *reinterpret_cast<const float4*>(x + base + lane * 4);
    const float4 v2 = *reinterpret_cast<const float4*>(x + base + 256 + lane * 4);
    const float wa = w_seg[sl], wb = w_seg[sl + 4];
    float q0 = wa * v1.x + wb * v2.x;
    float q1 = wa * v1.y + wb * v2.y;
    float q2 = wa * v1.z + wb * v2.z;
    float q3 = wa * v1.w + wb * v2.w;
    q0 += __shfl_xor(q0, 16); q1 += __shfl_xor(q1, 16);
    q2 += __shfl_xor(q2, 16); q3 += __shfl_xor(q3, 16);
    q0 += __shfl_xor(q0, 32); q1 += __shfl_xor(q1, 32);
    q2 += __shfl_xor(q2, 32); q3 += __shfl_xor(q3, 32);
    u16x4 o1, o2;
    o1[0] = f2bf(v1.x + q0); o1[1] = f2bf(v1.y + q1);
    o1[2] = f2bf(v1.z + q2); o1[3] = f2bf(v1.w + q3);
    o2[0] = f2bf(v2.x + q0); o2[1] = f2bf(v2.y + q1);
    o2[2] = f2bf(v2.z + q2); o2[3] = f2bf(v2.w + q3);
    *reinterpret_cast<u16x4*>(wsX + base + sl * 64 + c0) = o1;
    *reinterpret_cast<u16x4*>(wsX + base + (sl + 4) * 64 + c0) = o2;
  } else if (bid < 1536) {
    // ---- pe2[s][c] = PE + b_emb[c]*(1+Sw) + b_seg ----
    const int t = (bid - 1024) * 256 + tid;
    const int s = t >> 8;
    const int c0 = (t & 255) * 4;
    float Sw = 0.f;
#pragma unroll
    for (int i = 0; i < 8; ++i) Sw += w_seg[i];
    const float inv2pi = 0.15915494309189535f;
    const float KLOG = 0.02595256324130752f;  // log2(10000)/512
    const float d0 = exp2f(-(float)(c0 >> 1) * KLOG) * inv2pi;
    const float d1 = exp2f(-(float)((c0 >> 1) + 1) * KLOG) * inv2pi;
    const float fs = (float)s;
    const float4 eb = *reinterpret_cast<const float4*>(b_emb + c0);
    const float cb = b_seg[0];
    float4 pv;
    pv.x = __builtin_amdgcn_sinf(__builtin_amdgcn_fractf(fs * d0)) + eb.x * (1.f + Sw) + cb;
    pv.y = __builtin_amdgcn_sinf(__builtin_amdgcn_fractf(fs * d0 + 0.25f)) + eb.y * (1.f + Sw) + cb;
    pv.z = __builtin_amdgcn_sinf(__builtin_amdgcn_fractf(fs * d1)) + eb.z * (1.f + Sw) + cb;
    pv.w = __builtin_amdgcn_sinf(__builtin_amdgcn_fractf(fs * d1 + 0.25f)) + eb.w * (1.f + Sw) + cb;
    *reinterpret_cast<float4*>(wsPE + (size_t)t * 4) = pv;
  } else {
    // ---- W -> bf16 A-fragment layout (verified rounds 2/4/5) ----
    const int t = (bid - 1536) * 256 + tid;  // 0..8191
    const int cfg = t >> 7;
    const int kf = (t >> 6) & 1;
    const int lane = t & 63;
    const int col = cfg * 16 + (lane & 15);
    const int k0 = kf * 32 + ((lane >> 4) << 3);
    short8 o;
#pragma unroll
    for (int i = 0; i < 8; ++i)
      o[i] = (short)f2bf(W[(size_t)(k0 + i) * D_DIM + col]);
    *reinterpret_cast<short8*>(wsW + (size_t)t * 8) = o;
  }
}

__global__ __launch_bounds__(256) void bert_main(
    const unsigned short* __restrict__ wsX,
    const unsigned short* __restrict__ wsW, const float* __restrict__ wsPE,
    float* __restrict__ out) {
  __shared__ float ldse[32 * 256];  // 32 KB, XOR-swizzled
  char* const ldseB = (char*)ldse;

  const int tid = threadIdx.x;
  const int lane = tid & 63;
  const int w = tid >> 6;  // wave 0..3 = 64-col slice
  const int bid = blockIdx.x;
  // XCD swizzle: XCD k owns mblk === k (mod 8); its 4 col-tiles of a row-block
  // are consecutive -> x' L2-hit; pe2 slice per XCD = 64 rows (256 KB).
  const int k = bid & 7;
  const int j = bid >> 3;           // 0..511
  const int mblk = (j >> 2) * 8 + k;  // 0..1023 (32-row blocks)
  const int nblk = j & 3;             // 0..3 (256-col blocks)
  const int rbase = mblk * 32;
  const int nbase = nblk * 256;
  const int L15 = lane & 15;
  const int g = lane >> 4;

  // ---- A fragments: W cols nbase + w*64 + cf*16 (L2-hot) ----
  short8 aW[4][2];
#pragma unroll
  for (int cf = 0; cf < 4; ++cf)
#pragma unroll
    for (int kf = 0; kf < 2; ++kf) {
      const int cfg = (nbase >> 4) + w * 4 + cf;
      aW[cf][kf] = *reinterpret_cast<const short8*>(
          wsW + ((size_t)(cfg * 2 + kf) * 64 + lane) * 8);
    }

  // ---- B fragments: x' rows rbase + rf*16 + L15 ----
  short8 bX[2][2];
#pragma unroll
  for (int rf = 0; rf < 2; ++rf)
#pragma unroll
    for (int kf = 0; kf < 2; ++kf) {
      const int row = rbase + rf * 16 + L15;
      bX[rf][kf] = *reinterpret_cast<const short8*>(
          wsX + (size_t)row * 64 + kf * 32 + g * 8);
    }

  // ---- MFMA ----
  f32x4 acc[4][2];
#pragma unroll
  for (int cf = 0; cf < 4; ++cf)
#pragma unroll
    for (int rf = 0; rf < 2; ++rf) {
      f32x4 c = {0.f, 0.f, 0.f, 0.f};
      c = __builtin_amdgcn_mfma_f32_16x16x32_bf16(aW[cf][0], bX[rf][0], c, 0, 0, 0);
      c = __builtin_amdgcn_mfma_f32_16x16x32_bf16(aW[cf][1], bX[rf][1], c, 0, 0, 0);
      acc[cf][rf] = c;
    }

  // ---- acc -> swizzled LDS (<=2-way bank use: free) ----
#pragma unroll
  for (int cf = 0; cf < 4; ++cf)
#pragma unroll
    for (int rf = 0; rf < 2; ++rf) {
      const int row = rf * 16 + L15;                // 0..31
      const int col = w * 64 + cf * 16 + g * 4;     // 0..255
      *reinterpret_cast<f32x4*>(
          ldseB + ((row * 1024 + col * 4) ^ ((row & 7) << 4))) = acc[cf][rf];
    }
  __syncthreads();

  // ---- store: one full tile-row per wave-instr = 1KB contiguous; pe2 read
  //      identical pattern (coalesced L2). ----
#pragma unroll
  for (int p = 0; p < 8; ++p) {
    const int row = p * 4 + w;  // 0..31
    const f32x4 v = *reinterpret_cast<const f32x4*>(
        ldseB + ((row * 1024 + lane * 16) ^ ((row & 7) << 4)));
    const float4 pe = *reinterpret_cast<const float4*>(
        wsPE + (size_t)((rbase + row) & 511) * D_DIM + nbase + lane * 4);
    float4 o;
    o.x = v[0] + pe.x;
    o.y = v[1] + pe.y;
    o.z = v[2] + pe.z;
    o.w = v[3] + pe.w;
    *reinterpret_cast<float4*>(out + (size_t)(rbase + row) * D_DIM + nbase +
                               lane * 4) = o;
  }
}

extern "C" void kernel_launch(void* const* d_in, const int* in_sizes, int n_in,
                              void* d_out, int out_size, void* d_ws,
                              size_t ws_size, hipStream_t stream) {
  const float* x = (const float*)d_in[0];
  const float* W = (const float*)d_in[1];
  const float* b_emb = (const float*)d_in[2];
  const float* w_seg = (const float*)d_in[3];
  const float* b_seg = (const float*)d_in[4];
  float* out = (float*)d_out;

  unsigned short* wsW = (unsigned short*)d_ws;                      // 128 KB
  float* wsPE = (float*)((char*)d_ws + WS_PE_OFF);                  // 2 MB
  unsigned short* wsX = (unsigned short*)((char*)d_ws + WS_X_OFF);  // 4 MB

  bert_setup<<<1568, 256, 0, stream>>>(x, W, b_emb, w_seg, b_seg, wsW, wsPE, wsX);
  bert_main<<<4096, 256, 0, stream>>>(wsX, wsW, wsPE, out);
}